// Round 4
// baseline (822.529 us; speedup 1.0000x reference)
//
#include <hip/hip_runtime.h>
#include <cstdint>

#define TT   1024
#define HH   1024
#define EE   64
#define KK   6
#define GG   8
#define TGn  4
#define FF   512
#define FN   1024   // F*NSH
#define CAPc 384
#define SCALEs 2.5f

typedef unsigned int u32;
typedef unsigned short u16;
typedef short short8 __attribute__((ext_vector_type(8)));
typedef float f32x4 __attribute__((ext_vector_type(4)));
union ABu { uint4 u; short8 s; };

// round-half-up fp32->bf16, two at once
__device__ __forceinline__ u32 pack_bf16(float a, float b) {
  u32 ua = __float_as_uint(a) + 0x8000u;
  u32 ub = __float_as_uint(b) + 0x8000u;
  return __builtin_amdgcn_perm(ub, ua, 0x07060302u);
}
__device__ __forceinline__ u16 bf16_1(float a) {
  return (u16)((__float_as_uint(a) + 0x8000u) >> 16);
}
__device__ __forceinline__ float bf2f(u32 lo16) {
  return __uint_as_float(lo16 << 16);
}

// ============ fused: x->bf16 convert + gate + grouped top-k + dispatch ======
__global__ __launch_bounds__(256) void gate_fused(
    const float* __restrict__ x, const float* __restrict__ gw,
    const float* __restrict__ bias, u32* __restrict__ xb,
    int* __restrict__ counts, int* __restrict__ tok_of,
    int* __restrict__ ids, int* __restrict__ slot_of, float* __restrict__ tw) {
  __shared__ float xs[HH];
  __shared__ float part[256];
  __shared__ float sc[EE];
  __shared__ float scores[EE];
  const int t = blockIdx.x, tid = threadIdx.x;
  float4 v = ((const float4*)(x + (size_t)t * HH))[tid];
  ((float4*)xs)[tid] = v;
  uint2 o;
  o.x = pack_bf16(v.x, v.y);
  o.y = pack_bf16(v.z, v.w);
  ((uint2*)xb)[t * (HH / 4) + tid] = o;
  __syncthreads();
  {
    const int e = tid & 63, seg = tid >> 6;
    const float* w = gw + (size_t)e * HH + seg * 256;
    const float* xv = xs + seg * 256;
    float acc = 0.f;
#pragma unroll 8
    for (int i = 0; i < 256; ++i) acc = fmaf(xv[i], w[i], acc);
    part[tid] = acc;
  }
  __syncthreads();
  if (tid < 64) {
    float a = part[tid] + part[tid + 64] + part[tid + 128] + part[tid + 192];
    float s = 1.f / (1.f + expf(-a));
    scores[tid] = s;
    sc[tid] = s + bias[tid];
  }
  __syncthreads();
  if (tid == 0) {
    float gs[GG];
    for (int g = 0; g < GG; ++g) {
      float m1 = -1e30f, m2 = -1e30f;
      for (int j = 0; j < EE / GG; ++j) {
        float v2 = sc[g * (EE / GG) + j];
        if (v2 > m1) { m2 = m1; m1 = v2; }
        else if (v2 > m2) { m2 = v2; }
      }
      gs[g] = m1 + m2;
    }
    unsigned gmask = 0;
    for (int r = 0; r < TGn; ++r) {
      int best = -1; float bv = -1e30f;
      for (int g = 0; g < GG; ++g)
        if (!((gmask >> g) & 1u) && gs[g] > bv) { bv = gs[g]; best = g; }
      gmask |= 1u << best;
    }
    unsigned long long used = 0ull;
    float wsum = 0.f;
    int idbuf[KK]; float wbuf[KK];
    for (int r = 0; r < KK; ++r) {
      int best = -1; float bv = -3e38f;
      for (int e = 0; e < EE; ++e) {
        if (!((gmask >> (e / (EE / GG))) & 1u)) continue;
        if ((used >> e) & 1ull) continue;
        float v2 = sc[e];
        if (v2 > bv) { bv = v2; best = e; }
      }
      used |= 1ull << best;
      idbuf[r] = best;
      wbuf[r] = scores[best];
      wsum += scores[best];
    }
    const float inv = SCALEs / wsum;
    for (int r = 0; r < KK; ++r) {
      const int e = idbuf[r];
      const int p = atomicAdd(&counts[e], 1);
      if (p < CAPc) tok_of[e * CAPc + p] = t;
      ids[t * KK + r] = e;
      slot_of[t * KK + r] = p;
      tw[t * KK + r] = wbuf[r] * inv;
    }
  }
}

// LDS strides (dwords)
#define SA 20
#define SB 132
#define SB2 68

// ================= GEMM1: act = silu(X@W[:, :FH]) * (X@W[:, FH:]) ===========
// block tile MT x (64 gate + 64 up), depth-2 register prefetch.
template<int MT, int FH, bool ROUTED>
__global__ __launch_bounds__(256) void gemm1_k(
    const u32* __restrict__ xb, const float* __restrict__ wsrc,
    const int* __restrict__ counts, const int* __restrict__ tok_of,
    u16* __restrict__ actp) {
  constexpr int WROW = 2 * FH;
  constexpr int RT = MT / 32;
  constexpr int ADW = MT * 16 / 256;      // A dwords staged per thread
  constexpr int AV = ADW / 4;             // uint4 per thread
  const int e = ROUTED ? blockIdx.z : 0;
  int n_e = MT;
  if (ROUTED) {
    n_e = min(counts[e], CAPc);
    if ((int)(blockIdx.y * MT) >= n_e) return;
  }
  const int m0 = blockIdx.y * MT;
  const int n0 = blockIdx.x * 64;
  __shared__ __align__(16) u32 As[MT * SA];
  __shared__ __align__(16) u32 Bs[16 * SB];
  __shared__ int toks[MT];
  const int tid = threadIdx.x;
  if (ROUTED) {
    for (int i = tid; i < MT; i += 256)
      toks[i] = (m0 + i < n_e) ? tok_of[e * CAPc + m0 + i] : -1;
    __syncthreads();
  }
  const int wave = tid >> 6, lane = tid & 63, quad = lane >> 4, l16 = lane & 15;
  const int ww = wave & 1, wr = wave >> 1;
  const float* W = wsrc + (ROUTED ? (size_t)e * HH * WROW : 0);
  const int arow_i = tid & (MT - 1);
  const int akd = (MT == 128 ? (tid >> 7) : (tid >> 6)) * ADW;
  bool aok = true;
  const u32* arow;
  if (ROUTED) {
    int tk = toks[arow_i];
    aok = tk >= 0;
    arow = xb + (size_t)(aok ? tk : 0) * (HH / 2);
  } else {
    arow = xb + (size_t)(m0 + arow_i) * (HH / 2);
  }
  const int bkd0 = tid >> 5, bn4 = (tid & 31) << 2;
  const int bcol = (bn4 < 64) ? (n0 + bn4) : (FH + n0 + (bn4 - 64));

  uint4 apf[2][AV];
  float4 bpf[2][2][2];
  auto prefetch = [&](int k0, int p) {
#pragma unroll
    for (int i = 0; i < AV; ++i) {
      uint4 v = *(const uint4*)(arow + (k0 >> 1) + akd + 4 * i);
      if (!aok) v = make_uint4(0u, 0u, 0u, 0u);
      apf[p][i] = v;
    }
#pragma unroll
    for (int i = 0; i < 2; ++i) {
      const float* ptr = W + (size_t)(k0 + 2 * (bkd0 + 8 * i)) * WROW + bcol;
      bpf[p][i][0] = *(const float4*)ptr;
      bpf[p][i][1] = *(const float4*)(ptr + WROW);
    }
  };
  prefetch(0, 0);
  prefetch(32, 1);
  f32x4 acc[RT][4] = {};
  for (int k0 = 0; k0 < HH; k0 += 32) {
    const int p = (k0 >> 5) & 1;
    __syncthreads();
#pragma unroll
    for (int i = 0; i < AV; ++i)
      *(uint4*)(&As[arow_i * SA + akd + 4 * i]) = apf[p][i];
#pragma unroll
    for (int i = 0; i < 2; ++i) {
      uint4 bv;
      bv.x = pack_bf16(bpf[p][i][0].x, bpf[p][i][1].x);
      bv.y = pack_bf16(bpf[p][i][0].y, bpf[p][i][1].y);
      bv.z = pack_bf16(bpf[p][i][0].z, bpf[p][i][1].z);
      bv.w = pack_bf16(bpf[p][i][0].w, bpf[p][i][1].w);
      *(uint4*)(&Bs[(bkd0 + 8 * i) * SB + bn4]) = bv;
    }
    __syncthreads();
    if (k0 + 64 < HH) prefetch(k0 + 64, p);
    ABu bfr[4];
#pragma unroll
    for (int j = 0; j < 4; ++j) {
      const int cb = (j < 2) ? (ww * 32 + j * 16) : (64 + ww * 32 + (j - 2) * 16);
      const int col = cb + l16;
      bfr[j].u.x = Bs[(quad * 4 + 0) * SB + col];
      bfr[j].u.y = Bs[(quad * 4 + 1) * SB + col];
      bfr[j].u.z = Bs[(quad * 4 + 2) * SB + col];
      bfr[j].u.w = Bs[(quad * 4 + 3) * SB + col];
    }
#pragma unroll
    for (int mi = 0; mi < RT; ++mi) {
      ABu a;
      a.u = *(const uint4*)(&As[(wr * (MT / 2) + mi * 16 + l16) * SA + quad * 4]);
#pragma unroll
      for (int j = 0; j < 4; ++j)
        acc[mi][j] = __builtin_amdgcn_mfma_f32_16x16x32_bf16(a.s, bfr[j].s, acc[mi][j], 0, 0, 0);
    }
  }
#pragma unroll
  for (int mi = 0; mi < RT; ++mi) {
#pragma unroll
    for (int j = 0; j < 2; ++j) {
      const int col = n0 + ww * 32 + j * 16 + l16;
#pragma unroll
      for (int r = 0; r < 4; ++r) {
        const int row = m0 + wr * (MT / 2) + mi * 16 + quad * 4 + r;
        const float g = acc[mi][j][r], u = acc[mi][j + 2][r];
        const float v = (g / (1.f + __expf(-g))) * u;
        size_t idx = ROUTED ? (((size_t)e * CAPc + row) * FH + col)
                            : ((size_t)row * FH + col);
        actp[idx] = bf16_1(v);
      }
    }
  }
}

// ================= GEMM2: out = A @ W  (A bf16 [rows][KD], W fp32 [KD][HH]) ==
// block tile MT x NT, depth-2 prefetch. routed -> bf16 eo; shared -> fp32 out.
template<int MT, int NT, int KD, bool ROUTED>
__global__ __launch_bounds__(256) void gemm2_k(
    const u32* __restrict__ asrc0, const float* __restrict__ wsrc,
    const int* __restrict__ counts, void* __restrict__ outp) {
  constexpr int RT = MT / 32;
  constexpr int CT = NT / 32;
  constexpr int ADW = MT * 16 / 256;
  constexpr int AV = ADW / 4;
  constexpr int SBX = (NT == 128) ? SB : SB2;
  const int e = ROUTED ? blockIdx.z : 0;
  if (ROUTED) {
    if ((int)(blockIdx.y * MT) >= min(counts[e], CAPc)) return;
  }
  const int m0 = blockIdx.y * MT;
  const int n0 = blockIdx.x * NT;
  __shared__ __align__(16) u32 As[MT * SA];
  __shared__ __align__(16) u32 Bs[16 * SBX];
  const int tid = threadIdx.x;
  const int wave = tid >> 6, lane = tid & 63, quad = lane >> 4, l16 = lane & 15;
  const int ww = wave & 1, wr = wave >> 1;
  const float* W = wsrc + (ROUTED ? (size_t)e * KD * HH : 0);
  const int arow_i = tid & (MT - 1);
  const int akd = (MT == 128 ? (tid >> 7) : (tid >> 6)) * ADW;
  const u32* arow = asrc0 + (ROUTED ? ((size_t)e * CAPc + m0 + arow_i) * (KD / 2)
                                    : (size_t)(m0 + arow_i) * (KD / 2));
  const int bkd0 = (NT == 128) ? (tid >> 5) : (tid >> 4);
  const int bn4 = (NT == 128) ? ((tid & 31) << 2) : ((tid & 15) << 2);
  constexpr int BI = (NT == 128) ? 2 : 1;

  uint4 apf[2][AV];
  float4 bpf[2][BI][2];
  auto prefetch = [&](int k0, int p) {
#pragma unroll
    for (int i = 0; i < AV; ++i)
      apf[p][i] = *(const uint4*)(arow + (k0 >> 1) + akd + 4 * i);
#pragma unroll
    for (int i = 0; i < BI; ++i) {
      const float* ptr = W + (size_t)(k0 + 2 * (bkd0 + 8 * i)) * HH + n0 + bn4;
      bpf[p][i][0] = *(const float4*)ptr;
      bpf[p][i][1] = *(const float4*)(ptr + HH);
    }
  };
  prefetch(0, 0);
  prefetch(32, 1);
  f32x4 acc[RT][CT] = {};
  for (int k0 = 0; k0 < KD; k0 += 32) {
    const int p = (k0 >> 5) & 1;
    __syncthreads();
#pragma unroll
    for (int i = 0; i < AV; ++i)
      *(uint4*)(&As[arow_i * SA + akd + 4 * i]) = apf[p][i];
#pragma unroll
    for (int i = 0; i < BI; ++i) {
      uint4 bv;
      bv.x = pack_bf16(bpf[p][i][0].x, bpf[p][i][1].x);
      bv.y = pack_bf16(bpf[p][i][0].y, bpf[p][i][1].y);
      bv.z = pack_bf16(bpf[p][i][0].z, bpf[p][i][1].z);
      bv.w = pack_bf16(bpf[p][i][0].w, bpf[p][i][1].w);
      *(uint4*)(&Bs[(bkd0 + 8 * i) * SBX + bn4]) = bv;
    }
    __syncthreads();
    if (k0 + 64 < KD) prefetch(k0 + 64, p);
    ABu bfr[CT];
#pragma unroll
    for (int j = 0; j < CT; ++j) {
      const int col = ww * (NT / 2) + j * 16 + l16;
      bfr[j].u.x = Bs[(quad * 4 + 0) * SBX + col];
      bfr[j].u.y = Bs[(quad * 4 + 1) * SBX + col];
      bfr[j].u.z = Bs[(quad * 4 + 2) * SBX + col];
      bfr[j].u.w = Bs[(quad * 4 + 3) * SBX + col];
    }
#pragma unroll
    for (int mi = 0; mi < RT; ++mi) {
      ABu a;
      a.u = *(const uint4*)(&As[(wr * (MT / 2) + mi * 16 + l16) * SA + quad * 4]);
#pragma unroll
      for (int j = 0; j < CT; ++j)
        acc[mi][j] = __builtin_amdgcn_mfma_f32_16x16x32_bf16(a.s, bfr[j].s, acc[mi][j], 0, 0, 0);
    }
  }
#pragma unroll
  for (int mi = 0; mi < RT; ++mi) {
#pragma unroll
    for (int j = 0; j < CT; ++j) {
      const int col = n0 + ww * (NT / 2) + j * 16 + l16;
#pragma unroll
      for (int r = 0; r < 4; ++r) {
        const int row = m0 + wr * (MT / 2) + mi * 16 + quad * 4 + r;
        if (ROUTED) {
          ((u16*)outp)[((size_t)e * CAPc + row) * HH + col] = bf16_1(acc[mi][j][r]);
        } else {
          ((float*)outp)[(size_t)row * HH + col] = acc[mi][j][r];
        }
      }
    }
  }
}

// ---------------- combine: out[t] += sum_k w_k * eo[e_k][slot_k] ------------
__global__ __launch_bounds__(256) void combine_k(
    const u16* __restrict__ eo, const int* __restrict__ ids,
    const int* __restrict__ slot_of, const float* __restrict__ tw,
    float* __restrict__ out) {
  const int t = blockIdx.x, tid = threadIdx.x;
  __shared__ int se[KK];
  __shared__ int ssl[KK];
  __shared__ float swt[KK];
  if (tid < KK) {
    se[tid] = ids[t * KK + tid];
    ssl[tid] = slot_of[t * KK + tid];
    swt[tid] = tw[t * KK + tid];
  }
  __syncthreads();
  const int h = tid * 4;
  float4 o = *(float4*)(&out[(size_t)t * HH + h]);
#pragma unroll
  for (int k = 0; k < KK; ++k) {
    if (ssl[k] >= CAPc) continue;
    const float wgt = swt[k];
    const u16* p = eo + ((size_t)se[k] * CAPc + ssl[k]) * HH + h;
    uint2 v = *(const uint2*)p;
    o.x = fmaf(wgt, bf2f(v.x & 0xffffu), o.x);
    o.y = fmaf(wgt, bf2f(v.x >> 16), o.y);
    o.z = fmaf(wgt, bf2f(v.y & 0xffffu), o.z);
    o.w = fmaf(wgt, bf2f(v.y >> 16), o.w);
  }
  *(float4*)(&out[(size_t)t * HH + h]) = o;
}

extern "C" void kernel_launch(void* const* d_in, const int* in_sizes, int n_in,
                              void* d_out, int out_size, void* d_ws, size_t ws_size,
                              hipStream_t stream) {
  const float* x    = (const float*)d_in[0];
  const float* gw   = (const float*)d_in[1];
  const float* bias = (const float*)d_in[2];
  const float* w13  = (const float*)d_in[3];
  const float* w2   = (const float*)d_in[4];
  const float* sw13 = (const float*)d_in[5];
  const float* sw2  = (const float*)d_in[6];
  float* out = (float*)d_out;

  char* ws = (char*)d_ws;
  size_t off = 0;
  int*   counts  = (int*)(ws + off);   off += 256;
  int*   tok_of  = (int*)(ws + off);   off += (size_t)EE * CAPc * 4;
  int*   ids     = (int*)(ws + off);   off += (size_t)TT * KK * 4;
  int*   slot_of = (int*)(ws + off);   off += (size_t)TT * KK * 4;
  float* tw      = (float*)(ws + off); off += (size_t)TT * KK * 4;
  off = (off + 255) & ~(size_t)255;
  u32*   xb      = (u32*)(ws + off);   off += (size_t)TT * HH * 2;         // 2 MB
  u16*   act     = (u16*)(ws + off);   off += (size_t)EE * CAPc * FF * 2;  // 25 MB
  u16*   eo      = (u16*)(ws + off);   off += (size_t)EE * CAPc * HH * 2;  // 50 MB
  u16*   act_s   = (u16*)(ws + off);   off += (size_t)TT * FN * 2;         // 2 MB

  hipMemsetAsync(counts, 0, 256, stream);
  gate_fused<<<TT, 256, 0, stream>>>(x, gw, bias, xb, counts, tok_of, ids, slot_of, tw);
  // routed experts
  gemm1_k<128, FF, true><<<dim3(FF / 64, CAPc / 128, EE), 256, 0, stream>>>(
      xb, w13, counts, tok_of, act);
  gemm2_k<128, 128, FF, true><<<dim3(HH / 128, CAPc / 128, EE), 256, 0, stream>>>(
      (const u32*)act, w2, counts, eo);
  // shared experts
  gemm1_k<64, FN, false><<<dim3(FN / 64, TT / 64), 256, 0, stream>>>(
      xb, sw13, nullptr, nullptr, act_s);
  gemm2_k<64, 64, FN, false><<<dim3(HH / 64, TT / 64), 256, 0, stream>>>(
      (const u32*)act_s, sw2, nullptr, out);
  // combine
  combine_k<<<TT, 256, 0, stream>>>(eo, ids, slot_of, tw, out);
}

// Round 5
// 657.030 us; speedup vs baseline: 1.2519x; 1.2519x over previous
//
#include <hip/hip_runtime.h>
#include <cstdint>

#define TT   1024
#define HH   1024
#define EE   64
#define KK   6
#define GG   8
#define TGn  4
#define FF   512
#define FN   1024   // F*NSH
#define CAPc 384
#define SCALEs 2.5f

typedef unsigned int u32;
typedef unsigned short u16;
typedef short short8 __attribute__((ext_vector_type(8)));
typedef float f32x4 __attribute__((ext_vector_type(4)));
union ABu { uint4 u; short8 s; };

// round-half-up fp32->bf16, two at once
__device__ __forceinline__ u32 pack_bf16(float a, float b) {
  u32 ua = __float_as_uint(a) + 0x8000u;
  u32 ub = __float_as_uint(b) + 0x8000u;
  return __builtin_amdgcn_perm(ub, ua, 0x07060302u);
}
__device__ __forceinline__ u16 bf16_1(float a) {
  return (u16)((__float_as_uint(a) + 0x8000u) >> 16);
}
__device__ __forceinline__ float bf2f(u32 lo16) {
  return __uint_as_float(lo16 << 16);
}

// ============ fused: x->bf16 convert + gate + grouped top-k + dispatch ======
__global__ __launch_bounds__(256) void gate_fused(
    const float* __restrict__ x, const float* __restrict__ gw,
    const float* __restrict__ bias, u32* __restrict__ xb,
    int* __restrict__ counts, int* __restrict__ tok_of,
    int* __restrict__ ids, int* __restrict__ slot_of, float* __restrict__ tw) {
  __shared__ float xs[HH];
  __shared__ float part[256];
  __shared__ float sc[EE];
  __shared__ float scores[EE];
  const int t = blockIdx.x, tid = threadIdx.x;
  float4 v = ((const float4*)(x + (size_t)t * HH))[tid];
  ((float4*)xs)[tid] = v;
  uint2 o;
  o.x = pack_bf16(v.x, v.y);
  o.y = pack_bf16(v.z, v.w);
  ((uint2*)xb)[t * (HH / 4) + tid] = o;
  __syncthreads();
  {
    const int e = tid & 63, seg = tid >> 6;
    const float* w = gw + (size_t)e * HH + seg * 256;
    const float* xv = xs + seg * 256;
    float acc = 0.f;
#pragma unroll 8
    for (int i = 0; i < 256; ++i) acc = fmaf(xv[i], w[i], acc);
    part[tid] = acc;
  }
  __syncthreads();
  if (tid < 64) {
    float a = part[tid] + part[tid + 64] + part[tid + 128] + part[tid + 192];
    float s = 1.f / (1.f + expf(-a));
    scores[tid] = s;
    sc[tid] = s + bias[tid];
  }
  __syncthreads();
  if (tid == 0) {
    float gs[GG];
    for (int g = 0; g < GG; ++g) {
      float m1 = -1e30f, m2 = -1e30f;
      for (int j = 0; j < EE / GG; ++j) {
        float v2 = sc[g * (EE / GG) + j];
        if (v2 > m1) { m2 = m1; m1 = v2; }
        else if (v2 > m2) { m2 = v2; }
      }
      gs[g] = m1 + m2;
    }
    unsigned gmask = 0;
    for (int r = 0; r < TGn; ++r) {
      int best = -1; float bv = -1e30f;
      for (int g = 0; g < GG; ++g)
        if (!((gmask >> g) & 1u) && gs[g] > bv) { bv = gs[g]; best = g; }
      gmask |= 1u << best;
    }
    unsigned long long used = 0ull;
    float wsum = 0.f;
    int idbuf[KK]; float wbuf[KK];
    for (int r = 0; r < KK; ++r) {
      int best = -1; float bv = -3e38f;
      for (int e = 0; e < EE; ++e) {
        if (!((gmask >> (e / (EE / GG))) & 1u)) continue;
        if ((used >> e) & 1ull) continue;
        float v2 = sc[e];
        if (v2 > bv) { bv = v2; best = e; }
      }
      used |= 1ull << best;
      idbuf[r] = best;
      wbuf[r] = scores[best];
      wsum += scores[best];
    }
    const float inv = SCALEs / wsum;
    for (int r = 0; r < KK; ++r) {
      const int e = idbuf[r];
      const int p = atomicAdd(&counts[e], 1);
      if (p < CAPc) tok_of[e * CAPc + p] = t;
      ids[t * KK + r] = e;
      slot_of[t * KK + r] = p;
      tw[t * KK + r] = wbuf[r] * inv;
    }
  }
}

// LDS strides (dwords)
#define SA 20
#define SB 132
#define SB2 68

// ================= GEMM1: act = silu(X@W[:, :FH]) * (X@W[:, FH:]) ===========
// block tile MT x (64 gate + 64 up). Depth-2 prefetch via NAMED buffer sets
// (no dynamic indexing -> no scratch spill; see R4 post-mortem).
template<int MT, int FH, bool ROUTED>
__global__ __launch_bounds__(256) void gemm1_k(
    const u32* __restrict__ xb, const float* __restrict__ wsrc,
    const int* __restrict__ counts, const int* __restrict__ tok_of,
    u16* __restrict__ actp) {
  constexpr int WROW = 2 * FH;
  constexpr int RT = MT / 32;
  constexpr int ADW = MT * 16 / 256;      // A dwords staged per thread
  constexpr int AV = ADW / 4;             // uint4 per thread
  const int e = ROUTED ? blockIdx.z : 0;
  int n_e = MT;
  if (ROUTED) {
    n_e = min(counts[e], CAPc);
    if ((int)(blockIdx.y * MT) >= n_e) return;
  }
  const int m0 = blockIdx.y * MT;
  const int n0 = blockIdx.x * 64;
  __shared__ __align__(16) u32 As[MT * SA];
  __shared__ __align__(16) u32 Bs[16 * SB];
  __shared__ int toks[MT];
  const int tid = threadIdx.x;
  if (ROUTED) {
    for (int i = tid; i < MT; i += 256)
      toks[i] = (m0 + i < n_e) ? tok_of[e * CAPc + m0 + i] : -1;
    __syncthreads();
  }
  const int wave = tid >> 6, lane = tid & 63, quad = lane >> 4, l16 = lane & 15;
  const int ww = wave & 1, wr = wave >> 1;
  const float* W = wsrc + (ROUTED ? (size_t)e * HH * WROW : 0);
  const int arow_i = tid & (MT - 1);
  const int akd = (MT == 128 ? (tid >> 7) : (tid >> 6)) * ADW;
  bool aok = true;
  const u32* arow;
  if (ROUTED) {
    int tk = toks[arow_i];
    aok = tk >= 0;
    arow = xb + (size_t)(aok ? tk : 0) * (HH / 2);
  } else {
    arow = xb + (size_t)(m0 + arow_i) * (HH / 2);
  }
  const int bkd0 = tid >> 5, bn4 = (tid & 31) << 2;
  const int bcol = (bn4 < 64) ? (n0 + bn4) : (FH + n0 + (bn4 - 64));

  uint4 aA[AV], aB[AV];
  float4 bA[2][2], bB[2][2];
  auto pf = [&](int k0, uint4 (&ap)[AV], float4 (&bp)[2][2]) {
#pragma unroll
    for (int i = 0; i < AV; ++i) {
      uint4 vv = *(const uint4*)(arow + (k0 >> 1) + akd + 4 * i);
      if (!aok) vv = make_uint4(0u, 0u, 0u, 0u);
      ap[i] = vv;
    }
#pragma unroll
    for (int i = 0; i < 2; ++i) {
      const float* ptr = W + (size_t)(k0 + 2 * (bkd0 + 8 * i)) * WROW + bcol;
      bp[i][0] = *(const float4*)ptr;
      bp[i][1] = *(const float4*)(ptr + WROW);
    }
  };
  f32x4 acc[RT][4] = {};
  auto stage = [&](uint4 (&ap)[AV], float4 (&bp)[2][2]) {
    __syncthreads();
#pragma unroll
    for (int i = 0; i < AV; ++i)
      *(uint4*)(&As[arow_i * SA + akd + 4 * i]) = ap[i];
#pragma unroll
    for (int i = 0; i < 2; ++i) {
      uint4 bv;
      bv.x = pack_bf16(bp[i][0].x, bp[i][1].x);
      bv.y = pack_bf16(bp[i][0].y, bp[i][1].y);
      bv.z = pack_bf16(bp[i][0].z, bp[i][1].z);
      bv.w = pack_bf16(bp[i][0].w, bp[i][1].w);
      *(uint4*)(&Bs[(bkd0 + 8 * i) * SB + bn4]) = bv;
    }
    __syncthreads();
  };
  auto domfma = [&]() {
    ABu bfr[4];
#pragma unroll
    for (int j = 0; j < 4; ++j) {
      const int cb = (j < 2) ? (ww * 32 + j * 16) : (64 + ww * 32 + (j - 2) * 16);
      const int col = cb + l16;
      bfr[j].u.x = Bs[(quad * 4 + 0) * SB + col];
      bfr[j].u.y = Bs[(quad * 4 + 1) * SB + col];
      bfr[j].u.z = Bs[(quad * 4 + 2) * SB + col];
      bfr[j].u.w = Bs[(quad * 4 + 3) * SB + col];
    }
#pragma unroll
    for (int mi = 0; mi < RT; ++mi) {
      ABu a;
      a.u = *(const uint4*)(&As[(wr * (MT / 2) + mi * 16 + l16) * SA + quad * 4]);
#pragma unroll
      for (int j = 0; j < 4; ++j)
        acc[mi][j] = __builtin_amdgcn_mfma_f32_16x16x32_bf16(a.s, bfr[j].s, acc[mi][j], 0, 0, 0);
    }
  };
  pf(0, aA, bA);
  pf(32, aB, bB);
  for (int k0 = 0; k0 < HH; k0 += 64) {
    stage(aA, bA);
    if (k0 + 64 < HH) pf(k0 + 64, aA, bA);
    domfma();
    stage(aB, bB);
    if (k0 + 96 < HH) pf(k0 + 96, aB, bB);
    domfma();
  }
#pragma unroll
  for (int mi = 0; mi < RT; ++mi) {
#pragma unroll
    for (int j = 0; j < 2; ++j) {
      const int col = n0 + ww * 32 + j * 16 + l16;
#pragma unroll
      for (int r = 0; r < 4; ++r) {
        const int row = m0 + wr * (MT / 2) + mi * 16 + quad * 4 + r;
        const float g = acc[mi][j][r], u = acc[mi][j + 2][r];
        const float v = (g / (1.f + __expf(-g))) * u;
        size_t idx = ROUTED ? (((size_t)e * CAPc + row) * FH + col)
                            : ((size_t)row * FH + col);
        actp[idx] = bf16_1(v);
      }
    }
  }
}

// ================= GEMM2: out = A @ W  (A bf16 [rows][KD], W fp32 [KD][HH]) ==
// block tile MT x NT, depth-2 named-buffer prefetch.
template<int MT, int NT, int KD, bool ROUTED>
__global__ __launch_bounds__(256) void gemm2_k(
    const u32* __restrict__ asrc0, const float* __restrict__ wsrc,
    const int* __restrict__ counts, void* __restrict__ outp) {
  constexpr int RT = MT / 32;
  constexpr int CT = NT / 32;
  constexpr int ADW = MT * 16 / 256;
  constexpr int AV = ADW / 4;
  constexpr int SBX = (NT == 128) ? SB : SB2;
  constexpr int BI = (NT == 128) ? 2 : 1;
  const int e = ROUTED ? blockIdx.z : 0;
  if (ROUTED) {
    if ((int)(blockIdx.y * MT) >= min(counts[e], CAPc)) return;
  }
  const int m0 = blockIdx.y * MT;
  const int n0 = blockIdx.x * NT;
  __shared__ __align__(16) u32 As[MT * SA];
  __shared__ __align__(16) u32 Bs[16 * SBX];
  const int tid = threadIdx.x;
  const int wave = tid >> 6, lane = tid & 63, quad = lane >> 4, l16 = lane & 15;
  const int ww = wave & 1, wr = wave >> 1;
  const float* W = wsrc + (ROUTED ? (size_t)e * KD * HH : 0);
  const int arow_i = tid & (MT - 1);
  const int akd = (MT == 128 ? (tid >> 7) : (tid >> 6)) * ADW;
  const u32* arow = asrc0 + (ROUTED ? ((size_t)e * CAPc + m0 + arow_i) * (KD / 2)
                                    : (size_t)(m0 + arow_i) * (KD / 2));
  const int bkd0 = (NT == 128) ? (tid >> 5) : (tid >> 4);
  const int bn4 = (NT == 128) ? ((tid & 31) << 2) : ((tid & 15) << 2);

  uint4 aA[AV], aB[AV];
  float4 bA[BI][2], bB[BI][2];
  auto pf = [&](int k0, uint4 (&ap)[AV], float4 (&bp)[BI][2]) {
#pragma unroll
    for (int i = 0; i < AV; ++i)
      ap[i] = *(const uint4*)(arow + (k0 >> 1) + akd + 4 * i);
#pragma unroll
    for (int i = 0; i < BI; ++i) {
      const float* ptr = W + (size_t)(k0 + 2 * (bkd0 + 8 * i)) * HH + n0 + bn4;
      bp[i][0] = *(const float4*)ptr;
      bp[i][1] = *(const float4*)(ptr + HH);
    }
  };
  f32x4 acc[RT][CT] = {};
  auto stage = [&](uint4 (&ap)[AV], float4 (&bp)[BI][2]) {
    __syncthreads();
#pragma unroll
    for (int i = 0; i < AV; ++i)
      *(uint4*)(&As[arow_i * SA + akd + 4 * i]) = ap[i];
#pragma unroll
    for (int i = 0; i < BI; ++i) {
      uint4 bv;
      bv.x = pack_bf16(bp[i][0].x, bp[i][1].x);
      bv.y = pack_bf16(bp[i][0].y, bp[i][1].y);
      bv.z = pack_bf16(bp[i][0].z, bp[i][1].z);
      bv.w = pack_bf16(bp[i][0].w, bp[i][1].w);
      *(uint4*)(&Bs[(bkd0 + 8 * i) * SBX + bn4]) = bv;
    }
    __syncthreads();
  };
  auto domfma = [&]() {
    ABu bfr[CT];
#pragma unroll
    for (int j = 0; j < CT; ++j) {
      const int col = ww * (NT / 2) + j * 16 + l16;
      bfr[j].u.x = Bs[(quad * 4 + 0) * SBX + col];
      bfr[j].u.y = Bs[(quad * 4 + 1) * SBX + col];
      bfr[j].u.z = Bs[(quad * 4 + 2) * SBX + col];
      bfr[j].u.w = Bs[(quad * 4 + 3) * SBX + col];
    }
#pragma unroll
    for (int mi = 0; mi < RT; ++mi) {
      ABu a;
      a.u = *(const uint4*)(&As[(wr * (MT / 2) + mi * 16 + l16) * SA + quad * 4]);
#pragma unroll
      for (int j = 0; j < CT; ++j)
        acc[mi][j] = __builtin_amdgcn_mfma_f32_16x16x32_bf16(a.s, bfr[j].s, acc[mi][j], 0, 0, 0);
    }
  };
  pf(0, aA, bA);
  pf(32, aB, bB);
  for (int k0 = 0; k0 < KD; k0 += 64) {
    stage(aA, bA);
    if (k0 + 64 < KD) pf(k0 + 64, aA, bA);
    domfma();
    stage(aB, bB);
    if (k0 + 96 < KD) pf(k0 + 96, aB, bB);
    domfma();
  }
#pragma unroll
  for (int mi = 0; mi < RT; ++mi) {
#pragma unroll
    for (int j = 0; j < CT; ++j) {
      const int col = n0 + ww * (NT / 2) + j * 16 + l16;
#pragma unroll
      for (int r = 0; r < 4; ++r) {
        const int row = m0 + wr * (MT / 2) + mi * 16 + quad * 4 + r;
        if (ROUTED) {
          ((u16*)outp)[((size_t)e * CAPc + row) * HH + col] = bf16_1(acc[mi][j][r]);
        } else {
          ((float*)outp)[(size_t)row * HH + col] = acc[mi][j][r];
        }
      }
    }
  }
}

// ---------------- combine: out[t] += sum_k w_k * eo[e_k][slot_k] ------------
__global__ __launch_bounds__(256) void combine_k(
    const u16* __restrict__ eo, const int* __restrict__ ids,
    const int* __restrict__ slot_of, const float* __restrict__ tw,
    float* __restrict__ out) {
  const int t = blockIdx.x, tid = threadIdx.x;
  __shared__ int se[KK];
  __shared__ int ssl[KK];
  __shared__ float swt[KK];
  if (tid < KK) {
    se[tid] = ids[t * KK + tid];
    ssl[tid] = slot_of[t * KK + tid];
    swt[tid] = tw[t * KK + tid];
  }
  __syncthreads();
  const int h = tid * 4;
  float4 o = *(float4*)(&out[(size_t)t * HH + h]);
#pragma unroll
  for (int k = 0; k < KK; ++k) {
    if (ssl[k] >= CAPc) continue;
    const float wgt = swt[k];
    const u16* p = eo + ((size_t)se[k] * CAPc + ssl[k]) * HH + h;
    uint2 v = *(const uint2*)p;
    o.x = fmaf(wgt, bf2f(v.x & 0xffffu), o.x);
    o.y = fmaf(wgt, bf2f(v.x >> 16), o.y);
    o.z = fmaf(wgt, bf2f(v.y & 0xffffu), o.z);
    o.w = fmaf(wgt, bf2f(v.y >> 16), o.w);
  }
  *(float4*)(&out[(size_t)t * HH + h]) = o;
}

extern "C" void kernel_launch(void* const* d_in, const int* in_sizes, int n_in,
                              void* d_out, int out_size, void* d_ws, size_t ws_size,
                              hipStream_t stream) {
  const float* x    = (const float*)d_in[0];
  const float* gw   = (const float*)d_in[1];
  const float* bias = (const float*)d_in[2];
  const float* w13  = (const float*)d_in[3];
  const float* w2   = (const float*)d_in[4];
  const float* sw13 = (const float*)d_in[5];
  const float* sw2  = (const float*)d_in[6];
  float* out = (float*)d_out;

  char* ws = (char*)d_ws;
  size_t off = 0;
  int*   counts  = (int*)(ws + off);   off += 256;
  int*   tok_of  = (int*)(ws + off);   off += (size_t)EE * CAPc * 4;
  int*   ids     = (int*)(ws + off);   off += (size_t)TT * KK * 4;
  int*   slot_of = (int*)(ws + off);   off += (size_t)TT * KK * 4;
  float* tw      = (float*)(ws + off); off += (size_t)TT * KK * 4;
  off = (off + 255) & ~(size_t)255;
  u32*   xb      = (u32*)(ws + off);   off += (size_t)TT * HH * 2;         // 2 MB
  u16*   act     = (u16*)(ws + off);   off += (size_t)EE * CAPc * FF * 2;  // 25 MB
  u16*   eo      = (u16*)(ws + off);   off += (size_t)EE * CAPc * HH * 2;  // 50 MB
  u16*   act_s   = (u16*)(ws + off);   off += (size_t)TT * FN * 2;         // 2 MB

  hipMemsetAsync(counts, 0, 256, stream);
  gate_fused<<<TT, 256, 0, stream>>>(x, gw, bias, xb, counts, tok_of, ids, slot_of, tw);
  // routed experts
  gemm1_k<128, FF, true><<<dim3(FF / 64, CAPc / 128, EE), 256, 0, stream>>>(
      xb, w13, counts, tok_of, act);
  gemm2_k<128, 128, FF, true><<<dim3(HH / 128, CAPc / 128, EE), 256, 0, stream>>>(
      (const u32*)act, w2, counts, eo);
  // shared experts
  gemm1_k<64, FN, false><<<dim3(FN / 64, TT / 64), 256, 0, stream>>>(
      xb, sw13, nullptr, nullptr, act_s);
  gemm2_k<64, 64, FN, false><<<dim3(HH / 64, TT / 64), 256, 0, stream>>>(
      (const u32*)act_s, sw2, nullptr, out);
  // combine
  combine_k<<<TT, 256, 0, stream>>>(eo, ids, slot_of, tw, out);
}